// Round 6
// baseline (192.607 us; speedup 1.0000x reference)
//
#include <hip/hip_runtime.h>

using short8 = __attribute__((ext_vector_type(8))) short;
using f32x4  = __attribute__((ext_vector_type(4))) float;

__device__ inline unsigned short f2bf(float f) {
  unsigned u = __float_as_uint(f);
  u += 0x7fffu + ((u >> 16) & 1u);
  return (unsigned short)(u >> 16);
}
__device__ inline float bf2f(short s) {
  return __uint_as_float(((unsigned)(unsigned short)s) << 16);
}

// barrier that waits LDS only — global loads stay outstanding (pipeline!)
__device__ inline void barrier_lgkm() {
  asm volatile("s_waitcnt lgkmcnt(0)\n\ts_barrier" ::: "memory");
}

// ------- Kernel 0a: x NCHW fp32 -> xT (bf16 hi) + xTlo (bf16 residual), NHWC -------
// grid 1024 = b(8) * y(64) * xhalf(2); fp32 tile [32][268]
__global__ __launch_bounds__(256) void prep_xT(const float* __restrict__ x,
                                               unsigned short* __restrict__ xT,
                                               unsigned short* __restrict__ xTlo) {
  __shared__ float tile[32 * 268];   // 34304 B
  int bid = blockIdx.x;
  int xh = bid & 1, y = (bid >> 1) & 63, b = bid >> 7;
  int tid = threadIdx.x;
  int xc = tid & 31, cq = tid >> 5;   // 32 sites x 8 c-slots
#pragma unroll 4
  for (int i = 0; i < 32; ++i) {
    int c = i * 8 + cq;
    tile[xc * 268 + c] =
        x[(((size_t)((b << 8) + c)) << 12) + (y << 6) + xh * 32 + xc];
  }
  __syncthreads();
#pragma unroll 2
  for (int i = 0; i < 8; ++i) {
    int u = i * 256 + tid;            // 2048 units of 4 ch
    int site = u >> 6, c4 = u & 63;
    float4 v = *(const float4*)(tile + site * 268 + c4 * 4);
    ushort4 hi, lo;
    hi.x = f2bf(v.x); lo.x = f2bf(v.x - bf2f(hi.x));
    hi.y = f2bf(v.y); lo.y = f2bf(v.y - bf2f(hi.y));
    hi.z = f2bf(v.z); lo.z = f2bf(v.z - bf2f(hi.z));
    hi.w = f2bf(v.w); lo.w = f2bf(v.w - bf2f(hi.w));
    size_t addr = (((size_t)((b << 12) + (y << 6) + xh * 32 + site)) << 8) + c4 * 4;
    *(ushort4*)(xT + addr) = hi;
    *(ushort4*)(xTlo + addr) = lo;
  }
}

// ------- Kernel 0b: both weight prep paths in one launch -------
// bid < 2304: conv weights -> wBt2[ks][o(256)][kc(32)] bf16
// bid >= 2304: offset weights -> wOt/wOtLo[ks][o(32, rows>=18 zero)][kc(32)]
__global__ void prep_w_all(const float* __restrict__ cw, const float* __restrict__ ow,
                           unsigned short* __restrict__ wBt2,
                           unsigned short* __restrict__ wOt,
                           unsigned short* __restrict__ wOtLo) {
  int bid = blockIdx.x;
  if (bid < 2304) {
    int e = bid * 256 + threadIdx.x;   // < 589824
    int kc = e & 31, o = (e >> 5) & 255, ks = e >> 13;
    int c = (ks & 7) * 32 + kc, kt = ks >> 3;
    wBt2[e] = f2bf(cw[(size_t)(o * 256 + c) * 9 + kt]);
  } else {
    int e = (bid - 2304) * 256 + threadIdx.x;   // < 73728
    int kc = e & 31, o = (e >> 5) & 31, ks = e >> 10;
    int c = (ks & 7) * 32 + kc, kt = ks >> 3;
    float v = (o < 18) ? ow[(size_t)(o * 256 + c) * 9 + kt] : 0.f;
    unsigned short hi = f2bf(v);
    wOt[e] = hi;
    wOtLo[e] = f2bf(v - bf2f(hi));
  }
}

// ------- offset-conv helpers -------
__device__ inline void gatherOff2(const unsigned short* xT, const unsigned short* xTlo,
                                  const unsigned short* zp, int b, int h, int p16,
                                  int q, int ccg, int ky, int kx,
                                  short8* gh, short8* gl) {
  int y = h + ky - 1;
  bool yv = (unsigned)y < 64u;
  int yc = min(max(y, 0), 63);
#pragma unroll
  for (int i = 0; i < 4; ++i) {
    int px = i * 16 + p16;
    int xx = px + kx - 1;
    bool v = yv && ((unsigned)xx < 64u);
    int xc = min(max(xx, 0), 63);
    size_t base = (((size_t)((b << 12) + (yc << 6) + xc)) << 8) + ccg * 32 + q * 8;
    const unsigned short* ph = v ? (xT + base) : zp;
    const unsigned short* pl = v ? (xTlo + base) : zp;
    gh[i] = *(const short8*)ph;
    gl[i] = *(const short8*)pl;
  }
}
__device__ inline void loadBOff2(const unsigned short* wOt, const unsigned short* wOtLo,
                                 int ks, int m16, int quad, short8* bh, short8* bl) {
  const unsigned short* bp = wOt + (ks << 10) + m16 * 32 + quad * 8;
  const unsigned short* bq = wOtLo + (ks << 10) + m16 * 32 + quad * 8;
  bh[0] = *(const short8*)bp;  bh[1] = *(const short8*)(bp + 512);
  bl[0] = *(const short8*)bq;  bl[1] = *(const short8*)(bq + 512);
}

// ------- Kernel 1: offset conv via MFMA — barrier-free, 1 wave/block -------
// grid 1024 = half(2) x h(64) x b(8). Wave owns (b,h,cc-half): M=64, N=32, K=1152.
// hi/lo split: acc += Ah*Bh + Al*Bh + Ah*Bl  (fp32-grade accuracy).
// Partials -> overlay inside `out` at channels 200+half*18+o (race-free; see notes).
__global__ __launch_bounds__(64) void offset_conv2(
    const unsigned short* __restrict__ xT, const unsigned short* __restrict__ xTlo,
    const unsigned short* __restrict__ wOt, const unsigned short* __restrict__ wOtLo,
    const unsigned short* __restrict__ zp, float* out) {
  __shared__ unsigned short Ah[2 * 2560], Al[2 * 2560];   // [buf][64][40]
  int lane = threadIdx.x;
  int bid = blockIdx.x;
  int b = bid & 7, h = (bid >> 3) & 63, half = bid >> 9;
  int m16 = lane & 15, quad = lane >> 4;
  int p16 = lane >> 2, q = lane & 3;
  int cc0 = half * 4;
  f32x4 acc[4][2];
#pragma unroll
  for (int mt = 0; mt < 4; ++mt)
#pragma unroll
    for (int j = 0; j < 2; ++j) acc[mt][j] = (f32x4){0.f, 0.f, 0.f, 0.f};

  short8 gh[4], gl[4], bh[2], bl[2];
  gatherOff2(xT, xTlo, zp, b, h, p16, q, cc0, 0, 0, gh, gl);
  loadBOff2(wOt, wOtLo, cc0, m16, quad, bh, bl);

  for (int it = 0; it < 36; ++it) {
    int buf = it & 1;
#pragma unroll
    for (int i = 0; i < 4; ++i) {
      int px = i * 16 + p16;
      *(short8*)(Ah + buf * 2560 + px * 40 + q * 8) = gh[i];
      *(short8*)(Al + buf * 2560 + px * 40 + q * 8) = gl[i];
    }
    // prefetch jn = it+1 (it=35 -> cc overruns into xTlo region: safe, discarded)
    int jn = it + 1;
    int ccn = cc0 + jn / 9, r9 = jn % 9;
    int kyn = r9 / 3, kxn = r9 - kyn * 3;
    short8 ghn[4], gln[4], bhn[2], bln[2];
    loadBOff2(wOt, wOtLo, (kyn * 3 + kxn) * 8 + ccn, m16, quad, bhn, bln);
    gatherOff2(xT, xTlo, zp, b, h, p16, q, ccn, kyn, kxn, ghn, gln);
    // wave-local LDS: compiler inserts lgkmcnt waits; no barrier needed
#pragma unroll
    for (int mt = 0; mt < 4; ++mt) {
      short8 ah = *(const short8*)(Ah + buf * 2560 + (mt * 16 + m16) * 40 + quad * 8);
      short8 al = *(const short8*)(Al + buf * 2560 + (mt * 16 + m16) * 40 + quad * 8);
#pragma unroll
      for (int j = 0; j < 2; ++j) {
        acc[mt][j] = __builtin_amdgcn_mfma_f32_16x16x32_bf16(ah, bh[j], acc[mt][j], 0, 0, 0);
        acc[mt][j] = __builtin_amdgcn_mfma_f32_16x16x32_bf16(al, bh[j], acc[mt][j], 0, 0, 0);
        acc[mt][j] = __builtin_amdgcn_mfma_f32_16x16x32_bf16(ah, bl[j], acc[mt][j], 0, 0, 0);
      }
    }
#pragma unroll
    for (int i = 0; i < 4; ++i) { gh[i] = ghn[i]; gl[i] = gln[i]; }
    bh[0] = bhn[0]; bh[1] = bhn[1]; bl[0] = bln[0]; bl[1] = bln[1];
  }
  // epilogue: D row = px (mt*16+quad*4+r), col = o (j*16+m16)
#pragma unroll
  for (int j = 0; j < 2; ++j) {
    int o = j * 16 + m16;
    if (o < 18) {
      float* po = out + (((size_t)((b << 8) + 200 + half * 18 + o)) << 12) + (h << 6);
#pragma unroll
      for (int mt = 0; mt < 4; ++mt)
#pragma unroll
        for (int rr = 0; rr < 4; ++rr)
          po[mt * 16 + quad * 4 + rr] = acc[mt][j][rr];
    }
  }
}

// ------- deform_main helpers (unchanged, verified) -------
__device__ inline void gather4(const unsigned short* __restrict__ xT,
                               int bbase, int q, int jt,
                               const int2* cif2, const float4* cwf4,
                               int px, short8* g, float4& wq) {
  int cc = jt / 9, kt = jt - cc * 9;
  int2 si = cif2[kt * 64 + px];
  wq = cwf4[kt * 64 + px];
  const unsigned short* base = xT + (size_t)(unsigned)(bbase + cc * 32 + q * 8);
  g[0] = *(const short8*)(base + si.x);
  g[1] = *(const short8*)(base + si.x + 256);
  g[2] = *(const short8*)(base + si.y);
  g[3] = *(const short8*)(base + si.y + 256);
}
__device__ inline void loadB(const unsigned short* __restrict__ wBt2, int wave,
                             int m16, int quad, int jt, short8* bf) {
  int cc = jt / 9, kt = jt - cc * 9;
  int ks = kt * 8 + cc;
  const unsigned short* bp =
      wBt2 + ((size_t)ks << 13) + (wave << 11) + m16 * 32 + quad * 8;
#pragma unroll
  for (int j = 0; j < 4; ++j)
    bf[j] = *(const short8*)(bp + j * 512);
}

// ------- Kernel 2: fused sample + MFMA GEMM (reads offset overlay from out) -------
__global__ __launch_bounds__(256, 2) void deform_main(
    const unsigned short* __restrict__ xT, const float* __restrict__ offb,
    const unsigned short* __restrict__ wBt2, float* out) {
  __shared__ float4 smem4[2080];               // 33280 B
  char* smem = (char*)smem4;
  float4* cwf4 = (float4*)smem;                          // 9216 B
  int2*   cif2 = (int2*)(smem + 9216);                   // 4608 B
  unsigned short* At = (unsigned short*)(smem + 13824);  // 2 x [64][40] bf16

  int tid = threadIdx.x, lane = tid & 63, wave = tid >> 6;
  int b = blockIdx.x & 7, h = blockIdx.x >> 3;

  // --- coord/bilinear precompute; offsets = slice0 + slice1 + bias ---
  size_t bb = ((size_t)(b << 8)) << 12;
  for (int it = tid; it < 576; it += 256) {
    int k = it >> 6, px = it & 63;
    int ky = k / 3, kx = k - ky * 3;
    int idx = (h << 6) + px;
    float dy = out[bb + (((size_t)(200 + 2 * k)) << 12) + idx] +
               out[bb + (((size_t)(218 + 2 * k)) << 12) + idx] + offb[2 * k];
    float dx = out[bb + (((size_t)(201 + 2 * k)) << 12) + idx] +
               out[bb + (((size_t)(219 + 2 * k)) << 12) + idx] + offb[2 * k + 1];
    float py = (float)(h - 1 + ky) + dy;
    float pxx = (float)(px - 1 + kx) + dx;
    float y0f = floorf(py), x0f = floorf(pxx);
    int y0 = (int)y0f, x0 = (int)x0f;
    float wy1 = py - y0f, wx1 = pxx - x0f;
    int xb; float wxl, wxr;
    if (x0 >= 0 && x0 <= 62)      { xb = x0; wxl = 1.f - wx1; wxr = wx1; }
    else if (x0 == -1)            { xb = 0;  wxl = wx1;       wxr = 0.f; }
    else if (x0 == 63)            { xb = 62; wxl = 0.f;       wxr = 1.f - wx1; }
    else                          { xb = 0;  wxl = 0.f;       wxr = 0.f; }
    float wy0v = ((unsigned)y0 < 64u) ? (1.f - wy1) : 0.f;
    float wy1v = ((unsigned)(y0 + 1) < 64u) ? wy1 : 0.f;
    int yc0 = min(max(y0, 0), 63), yc1 = min(max(y0 + 1, 0), 63);
    cwf4[it] = make_float4(wy0v * wxl, wy0v * wxr, wy1v * wxl, wy1v * wxr);
    cif2[it] = make_int2(((yc0 << 6) + xb) << 8, ((yc1 << 6) + xb) << 8);
  }
  __syncthreads();

  int m16 = lane & 15, quad = lane >> 4;
  int px = wave * 16 + (lane >> 2);
  int q  = lane & 3;
  int bbase = b << 20;
  f32x4 acc[4][4];
#pragma unroll
  for (int i = 0; i < 4; ++i)
#pragma unroll
    for (int j = 0; j < 4; ++j) acc[i][j] = (f32x4){0.f, 0.f, 0.f, 0.f};

  short8 g[4]; float4 wq; short8 bcur[4];
  gather4(xT, bbase, q, 0, cif2, cwf4, px, g, wq);
  loadB(wBt2, wave, m16, quad, 0, bcur);

  for (int it = 0; it < 72; ++it) {
    int buf = it & 1;
    short8 av;
#pragma unroll
    for (int i = 0; i < 8; ++i) {
      float v = wq.x * bf2f(g[0][i]) + wq.y * bf2f(g[1][i]) +
                wq.z * bf2f(g[2][i]) + wq.w * bf2f(g[3][i]);
      av[i] = (short)f2bf(v);
    }
    *(short8*)(At + buf * 2560 + px * 40 + q * 8) = av;
    int jn = (it < 71) ? it + 1 : 71;
    short8 bnext[4], gn[4]; float4 wqn;
    loadB(wBt2, wave, m16, quad, jn, bnext);
    gather4(xT, bbase, q, jn, cif2, cwf4, px, gn, wqn);
    barrier_lgkm();
    short8 af[4];
#pragma unroll
    for (int mt = 0; mt < 4; ++mt)
      af[mt] = *(const short8*)(At + buf * 2560 + (mt * 16 + m16) * 40 + quad * 8);
#pragma unroll
    for (int mt = 0; mt < 4; ++mt)
#pragma unroll
      for (int j = 0; j < 4; ++j)
        acc[mt][j] = __builtin_amdgcn_mfma_f32_16x16x32_bf16(af[mt], bcur[j],
                                                             acc[mt][j], 0, 0, 0);
#pragma unroll
    for (int i = 0; i < 4; ++i) g[i] = gn[i];
    wq = wqn;
#pragma unroll
    for (int j = 0; j < 4; ++j) bcur[j] = bnext[j];
  }
  __syncthreads();

  float* ep = (float*)smem;   // [128][65]
  for (int half = 0; half < 2; ++half) {
    if ((wave >> 1) == half) {
#pragma unroll
      for (int mt = 0; mt < 4; ++mt)
#pragma unroll
        for (int j = 0; j < 4; ++j)
#pragma unroll
          for (int rr = 0; rr < 4; ++rr) {
            int o_loc = (wave & 1) * 64 + j * 16 + m16;
            int ppx = mt * 16 + quad * 4 + rr;
            ep[o_loc * 65 + ppx] = acc[mt][j][rr];
          }
    }
    __syncthreads();
#pragma unroll 4
    for (int t = 0; t < 32; ++t) {
      int idx = t * 256 + tid;
      int o = idx >> 6, ppx = idx & 63;
      out[(((size_t)((b << 8) + half * 128 + o)) << 12) + (h << 6) + ppx] =
          ep[o * 65 + ppx];
    }
    __syncthreads();
  }
}

extern "C" void kernel_launch(void* const* d_in, const int* in_sizes, int n_in,
                              void* d_out, int out_size, void* d_ws, size_t ws_size,
                              hipStream_t stream) {
  const float* x     = (const float*)d_in[0];
  const float* offw  = (const float*)d_in[1];
  const float* offb  = (const float*)d_in[2];
  const float* convw = (const float*)d_in[3];
  float* out = (float*)d_out;

  char* ws = (char*)d_ws;
  unsigned short* wOt   = (unsigned short*)ws;                // 147,456 B
  unsigned short* wOtLo = (unsigned short*)(ws + 147456);     // 147,456 B
  unsigned short* wBt2  = (unsigned short*)(ws + 294912);     // 1,179,648 B
  unsigned short* xT    = (unsigned short*)(ws + 1474560);    // 16,777,216 B
  unsigned short* xTlo  = (unsigned short*)(ws + 18251776);   // 16,777,216 B (end 35,028,992)
  const unsigned short* zp = wOt + 768;   // ks=0, o=24 row: guaranteed zeros

  prep_xT<<<1024, 256, 0, stream>>>(x, xT, xTlo);
  prep_w_all<<<2592, 256, 0, stream>>>(convw, offw, wBt2, wOt, wOtLo);
  offset_conv2<<<1024, 64, 0, stream>>>(xT, xTlo, wOt, wOtLo, zp, out);
  deform_main<<<512, 256, 0, stream>>>(xT, offb, wBt2, out);
}

// Round 7
// 185.045 us; speedup vs baseline: 1.0409x; 1.0409x over previous
//
#include <hip/hip_runtime.h>

using short8 = __attribute__((ext_vector_type(8))) short;
using f32x4  = __attribute__((ext_vector_type(4))) float;

__device__ inline unsigned short f2bf(float f) {
  unsigned u = __float_as_uint(f);
  u += 0x7fffu + ((u >> 16) & 1u);
  return (unsigned short)(u >> 16);
}
__device__ inline float bf2f(short s) {
  return __uint_as_float(((unsigned)(unsigned short)s) << 16);
}

// barrier that waits LDS only — global loads stay outstanding (pipeline!)
__device__ inline void barrier_lgkm() {
  asm volatile("s_waitcnt lgkmcnt(0)\n\ts_barrier" ::: "memory");
}

// ------- Kernel 0: ALL prep in one launch -------
// bid < 1024:             x NCHW fp32 -> xT (hi) + xTlo (residual) NHWC bf16
// 1024 <= bid < 3328:     conv weights -> wBt2[ks][o(256)][kc(32)]
// bid >= 3328:            offset weights -> wOt/wOtLo[ks][o(32, >=18 zero)][kc(32)]
__global__ __launch_bounds__(256) void prep_all(
    const float* __restrict__ x, const float* __restrict__ cw,
    const float* __restrict__ ow, unsigned short* __restrict__ xT,
    unsigned short* __restrict__ xTlo, unsigned short* __restrict__ wBt2,
    unsigned short* __restrict__ wOt, unsigned short* __restrict__ wOtLo) {
  __shared__ float tile[32 * 268];   // 34304 B (xT path only)
  int bid = blockIdx.x, tid = threadIdx.x;
  if (bid < 1024) {
    int xh = bid & 1, y = (bid >> 1) & 63, b = bid >> 7;
    int xc = tid & 31, cq = tid >> 5;
#pragma unroll 4
    for (int i = 0; i < 32; ++i) {
      int c = i * 8 + cq;
      tile[xc * 268 + c] =
          x[(((size_t)((b << 8) + c)) << 12) + (y << 6) + xh * 32 + xc];
    }
    __syncthreads();
#pragma unroll 2
    for (int i = 0; i < 8; ++i) {
      int u = i * 256 + tid;
      int site = u >> 6, c4 = u & 63;
      float4 v = *(const float4*)(tile + site * 268 + c4 * 4);
      ushort4 hi, lo;
      hi.x = f2bf(v.x); lo.x = f2bf(v.x - bf2f(hi.x));
      hi.y = f2bf(v.y); lo.y = f2bf(v.y - bf2f(hi.y));
      hi.z = f2bf(v.z); lo.z = f2bf(v.z - bf2f(hi.z));
      hi.w = f2bf(v.w); lo.w = f2bf(v.w - bf2f(hi.w));
      size_t addr = (((size_t)((b << 12) + (y << 6) + xh * 32 + site)) << 8) + c4 * 4;
      *(ushort4*)(xT + addr) = hi;
      *(ushort4*)(xTlo + addr) = lo;
    }
  } else if (bid < 3328) {
    int e = (bid - 1024) * 256 + tid;   // < 589824
    int kc = e & 31, o = (e >> 5) & 255, ks = e >> 13;
    int c = (ks & 7) * 32 + kc, kt = ks >> 3;
    wBt2[e] = f2bf(cw[(size_t)(o * 256 + c) * 9 + kt]);
  } else {
    int e = (bid - 3328) * 256 + tid;   // < 73728
    int kc = e & 31, o = (e >> 5) & 31, ks = e >> 10;
    int c = (ks & 7) * 32 + kc, kt = ks >> 3;
    float v = (o < 18) ? ow[(size_t)(o * 256 + c) * 9 + kt] : 0.f;
    unsigned short hi = f2bf(v);
    wOt[e] = hi;
    wOtLo[e] = f2bf(v - bf2f(hi));
  }
}

// ------- offset-conv helpers -------
__device__ inline void gatherOff2(const unsigned short* xT, const unsigned short* xTlo,
                                  const unsigned short* zp, int b, int h, int p16,
                                  int q, int ccg, int ky, int kx,
                                  short8* gh, short8* gl) {
  int y = h + ky - 1;
  bool yv = (unsigned)y < 64u;
  int yc = min(max(y, 0), 63);
#pragma unroll
  for (int i = 0; i < 4; ++i) {
    int px = i * 16 + p16;
    int xx = px + kx - 1;
    bool v = yv && ((unsigned)xx < 64u);
    int xc = min(max(xx, 0), 63);
    size_t base = (((size_t)((b << 12) + (yc << 6) + xc)) << 8) + ccg * 32 + q * 8;
    const unsigned short* ph = v ? (xT + base) : zp;
    const unsigned short* pl = v ? (xTlo + base) : zp;
    gh[i] = *(const short8*)ph;
    gl[i] = *(const short8*)pl;
  }
}
__device__ inline void loadBOff2(const unsigned short* wOt, const unsigned short* wOtLo,
                                 int ks, int m16, int quad, short8* bh, short8* bl) {
  const unsigned short* bp = wOt + (ks << 10) + m16 * 32 + quad * 8;
  const unsigned short* bq = wOtLo + (ks << 10) + m16 * 32 + quad * 8;
  bh[0] = *(const short8*)bp;  bh[1] = *(const short8*)(bp + 512);
  bl[0] = *(const short8*)bq;  bl[1] = *(const short8*)(bq + 512);
}

// ------- Kernel 1: offset conv via MFMA — barrier-free, 8-way K-split -------
// grid 4096 = ccq(8) x h(64) x b(8); 1 wave/block, 16 waves/CU.
// Wave: M=64, N=32, K=288 (fixed 32-ch chunk, taps 0..8). hi/lo numerics.
// Partial -> overlay channels 100 + ccq*18 + o of `out` (rewritten later by
// deform_main's epilogue; writer touches only row h — race-free).
__global__ __launch_bounds__(64) void offset_conv3(
    const unsigned short* __restrict__ xT, const unsigned short* __restrict__ xTlo,
    const unsigned short* __restrict__ wOt, const unsigned short* __restrict__ wOtLo,
    const unsigned short* __restrict__ zp, float* out) {
  __shared__ unsigned short Ah[2 * 2560], Al[2 * 2560];   // [buf][64][40]
  int lane = threadIdx.x;
  int bid = blockIdx.x;
  int b = bid & 7, h = (bid >> 3) & 63, ccq = bid >> 9;
  int m16 = lane & 15, quad = lane >> 4;
  int p16 = lane >> 2, q = lane & 3;
  f32x4 acc[4][2];
#pragma unroll
  for (int mt = 0; mt < 4; ++mt)
#pragma unroll
    for (int j = 0; j < 2; ++j) acc[mt][j] = (f32x4){0.f, 0.f, 0.f, 0.f};

  short8 gh[4], gl[4], bh[2], bl[2];
  gatherOff2(xT, xTlo, zp, b, h, p16, q, ccq, 0, 0, gh, gl);
  loadBOff2(wOt, wOtLo, ccq, m16, quad, bh, bl);

  for (int it = 0; it < 9; ++it) {
    int buf = it & 1;
#pragma unroll
    for (int i = 0; i < 4; ++i) {
      int px = i * 16 + p16;
      *(short8*)(Ah + buf * 2560 + px * 40 + q * 8) = gh[i];
      *(short8*)(Al + buf * 2560 + px * 40 + q * 8) = gl[i];
    }
    int jn = (it < 8) ? it + 1 : 8;     // tap index (clamped; last discarded)
    int kyn = jn / 3, kxn = jn - kyn * 3;
    short8 ghn[4], gln[4], bhn[2], bln[2];
    loadBOff2(wOt, wOtLo, jn * 8 + ccq, m16, quad, bhn, bln);
    gatherOff2(xT, xTlo, zp, b, h, p16, q, ccq, kyn, kxn, ghn, gln);
    // wave-local LDS: same-wave DS ordering, no barrier needed
#pragma unroll
    for (int mt = 0; mt < 4; ++mt) {
      short8 ah = *(const short8*)(Ah + buf * 2560 + (mt * 16 + m16) * 40 + quad * 8);
      short8 al = *(const short8*)(Al + buf * 2560 + (mt * 16 + m16) * 40 + quad * 8);
#pragma unroll
      for (int j = 0; j < 2; ++j) {
        acc[mt][j] = __builtin_amdgcn_mfma_f32_16x16x32_bf16(ah, bh[j], acc[mt][j], 0, 0, 0);
        acc[mt][j] = __builtin_amdgcn_mfma_f32_16x16x32_bf16(al, bh[j], acc[mt][j], 0, 0, 0);
        acc[mt][j] = __builtin_amdgcn_mfma_f32_16x16x32_bf16(ah, bl[j], acc[mt][j], 0, 0, 0);
      }
    }
#pragma unroll
    for (int i = 0; i < 4; ++i) { gh[i] = ghn[i]; gl[i] = gln[i]; }
    bh[0] = bhn[0]; bh[1] = bhn[1]; bl[0] = bln[0]; bl[1] = bln[1];
  }
  // epilogue: D row = px (mt*16+quad*4+r), col = o (j*16+m16)
#pragma unroll
  for (int j = 0; j < 2; ++j) {
    int o = j * 16 + m16;
    if (o < 18) {
      float* po = out + (((size_t)((b << 8) + 100 + ccq * 18 + o)) << 12) + (h << 6);
#pragma unroll
      for (int mt = 0; mt < 4; ++mt)
#pragma unroll
        for (int rr = 0; rr < 4; ++rr)
          po[mt * 16 + quad * 4 + rr] = acc[mt][j][rr];
    }
  }
}

// ------- deform_main helpers (verified) -------
__device__ inline void gather4(const unsigned short* __restrict__ xT,
                               int bbase, int q, int jt,
                               const int2* cif2, const float4* cwf4,
                               int px, short8* g, float4& wq) {
  int cc = jt / 9, kt = jt - cc * 9;
  int2 si = cif2[kt * 64 + px];
  wq = cwf4[kt * 64 + px];
  const unsigned short* base = xT + (size_t)(unsigned)(bbase + cc * 32 + q * 8);
  g[0] = *(const short8*)(base + si.x);
  g[1] = *(const short8*)(base + si.x + 256);
  g[2] = *(const short8*)(base + si.y);
  g[3] = *(const short8*)(base + si.y + 256);
}
__device__ inline void loadB(const unsigned short* __restrict__ wBt2, int wave,
                             int m16, int quad, int jt, short8* bf) {
  int cc = jt / 9, kt = jt - cc * 9;
  int ks = kt * 8 + cc;
  const unsigned short* bp =
      wBt2 + ((size_t)ks << 13) + (wave << 11) + m16 * 32 + quad * 8;
#pragma unroll
  for (int j = 0; j < 4; ++j)
    bf[j] = *(const short8*)(bp + j * 512);
}

// ------- Kernel 2: fused sample + MFMA GEMM (reads offset overlay from out) -------
__global__ __launch_bounds__(256, 2) void deform_main(
    const unsigned short* __restrict__ xT, const float* __restrict__ offb,
    const unsigned short* __restrict__ wBt2, float* out) {
  __shared__ float4 smem4[1504];               // 24064 B
  char* smem = (char*)smem4;
  float4* cwf4 = (float4*)smem;                          // 9216 B
  int2*   cif2 = (int2*)(smem + 9216);                   // 4608 B
  unsigned short* At = (unsigned short*)(smem + 13824);  // 2 x [64][40] bf16

  int tid = threadIdx.x, lane = tid & 63, wave = tid >> 6;
  int b = blockIdx.x & 7, h = blockIdx.x >> 3;

  // --- coord precompute; offsets = sum of 8 K-split partials + bias ---
  size_t bb = ((size_t)(b << 8)) << 12;
  for (int it = tid; it < 576; it += 256) {
    int k = it >> 6, px = it & 63;
    int ky = k / 3, kx = k - ky * 3;
    int idx = (h << 6) + px;
    float dy = offb[2 * k], dx = offb[2 * k + 1];
#pragma unroll
    for (int qq = 0; qq < 8; ++qq) {
      dy += out[bb + (((size_t)(100 + qq * 18 + 2 * k)) << 12) + idx];
      dx += out[bb + (((size_t)(101 + qq * 18 + 2 * k)) << 12) + idx];
    }
    float py = (float)(h - 1 + ky) + dy;
    float pxx = (float)(px - 1 + kx) + dx;
    float y0f = floorf(py), x0f = floorf(pxx);
    int y0 = (int)y0f, x0 = (int)x0f;
    float wy1 = py - y0f, wx1 = pxx - x0f;
    int xb; float wxl, wxr;
    if (x0 >= 0 && x0 <= 62)      { xb = x0; wxl = 1.f - wx1; wxr = wx1; }
    else if (x0 == -1)            { xb = 0;  wxl = wx1;       wxr = 0.f; }
    else if (x0 == 63)            { xb = 62; wxl = 0.f;       wxr = 1.f - wx1; }
    else                          { xb = 0;  wxl = 0.f;       wxr = 0.f; }
    float wy0v = ((unsigned)y0 < 64u) ? (1.f - wy1) : 0.f;
    float wy1v = ((unsigned)(y0 + 1) < 64u) ? wy1 : 0.f;
    int yc0 = min(max(y0, 0), 63), yc1 = min(max(y0 + 1, 0), 63);
    cwf4[it] = make_float4(wy0v * wxl, wy0v * wxr, wy1v * wxl, wy1v * wxr);
    cif2[it] = make_int2(((yc0 << 6) + xb) << 8, ((yc1 << 6) + xb) << 8);
  }
  __syncthreads();

  int m16 = lane & 15, quad = lane >> 4;
  int px = wave * 16 + (lane >> 2);
  int q  = lane & 3;
  int bbase = b << 20;
  f32x4 acc[4][4];
#pragma unroll
  for (int i = 0; i < 4; ++i)
#pragma unroll
    for (int j = 0; j < 4; ++j) acc[i][j] = (f32x4){0.f, 0.f, 0.f, 0.f};

  short8 g[4]; float4 wq; short8 bcur[4];
  gather4(xT, bbase, q, 0, cif2, cwf4, px, g, wq);
  loadB(wBt2, wave, m16, quad, 0, bcur);

  for (int it = 0; it < 72; ++it) {
    int buf = it & 1;
    short8 av;
#pragma unroll
    for (int i = 0; i < 8; ++i) {
      float v = wq.x * bf2f(g[0][i]) + wq.y * bf2f(g[1][i]) +
                wq.z * bf2f(g[2][i]) + wq.w * bf2f(g[3][i]);
      av[i] = (short)f2bf(v);
    }
    *(short8*)(At + buf * 2560 + px * 40 + q * 8) = av;
    int jn = (it < 71) ? it + 1 : 71;
    short8 bnext[4], gn[4]; float4 wqn;
    loadB(wBt2, wave, m16, quad, jn, bnext);
    gather4(xT, bbase, q, jn, cif2, cwf4, px, gn, wqn);
    barrier_lgkm();
    short8 af[4];
#pragma unroll
    for (int mt = 0; mt < 4; ++mt)
      af[mt] = *(const short8*)(At + buf * 2560 + (mt * 16 + m16) * 40 + quad * 8);
#pragma unroll
    for (int mt = 0; mt < 4; ++mt)
#pragma unroll
      for (int j = 0; j < 4; ++j)
        acc[mt][j] = __builtin_amdgcn_mfma_f32_16x16x32_bf16(af[mt], bcur[j],
                                                             acc[mt][j], 0, 0, 0);
#pragma unroll
    for (int i = 0; i < 4; ++i) g[i] = gn[i];
    wq = wqn;
#pragma unroll
    for (int j = 0; j < 4; ++j) bcur[j] = bnext[j];
  }

  // ---- epilogue: direct float4 stores from D-fragments ----
  // o = wave*64 + j*16 + m16 ; px = mt*16 + quad*4 + r (r contiguous)
#pragma unroll
  for (int j = 0; j < 4; ++j) {
    int o = wave * 64 + j * 16 + m16;
    float* po = out + (((size_t)((b << 8) + o)) << 12) + (h << 6) + quad * 4;
#pragma unroll
    for (int mt = 0; mt < 4; ++mt) {
      float4 v = make_float4(acc[mt][j][0], acc[mt][j][1], acc[mt][j][2],
                             acc[mt][j][3]);
      *(float4*)(po + mt * 16) = v;
    }
  }
}

extern "C" void kernel_launch(void* const* d_in, const int* in_sizes, int n_in,
                              void* d_out, int out_size, void* d_ws, size_t ws_size,
                              hipStream_t stream) {
  const float* x     = (const float*)d_in[0];
  const float* offw  = (const float*)d_in[1];
  const float* offb  = (const float*)d_in[2];
  const float* convw = (const float*)d_in[3];
  float* out = (float*)d_out;

  char* ws = (char*)d_ws;
  unsigned short* wOt   = (unsigned short*)ws;                // 147,456 B
  unsigned short* wOtLo = (unsigned short*)(ws + 147456);     // 147,456 B
  unsigned short* wBt2  = (unsigned short*)(ws + 294912);     // 1,179,648 B
  unsigned short* xT    = (unsigned short*)(ws + 1474560);    // 16,777,216 B
  unsigned short* xTlo  = (unsigned short*)(ws + 18251776);   // 16,777,216 B (end 35,028,992)
  const unsigned short* zp = wOt + 768;   // ks=0, o=24 row: guaranteed zeros

  prep_all<<<3616, 256, 0, stream>>>(x, convw, offw, xT, xTlo, wBt2, wOt, wOtLo);
  offset_conv3<<<4096, 64, 0, stream>>>(xT, xTlo, wOt, wOtLo, zp, out);
  deform_main<<<512, 256, 0, stream>>>(xT, offb, wBt2, out);
}